// Round 9
// baseline (309.569 us; speedup 1.0000x reference)
//
#include <hip/hip_runtime.h>

#define SCALE 0.17677669529663687f  // 1/sqrt(32)
#define PSTR 513                    // padded logit row stride

// ---------------------------------------------------------------------------
// Grid 1024: i = bid&511 (query row), hg = bid>>9 (head-group). Pair (b,b+512)
// shares the e-slab and lands on the same XCD (512%8==0) -> L2 reuse.
// Block: 512 thr (8 waves), 4 local heads, ~13 KB LDS, VGPR target <=64.
//
// Prologue: q for our 4 heads; coef tables s_qce[c][hl], s_qcx[c][hl].
// P1 (coalesced): wave w owns rows [w*64,w*64+64). lane=(jj,part):
//   4 part-lanes cover one 64B line of a row per instr (16 lines/instr, no
//   redundant line requests vs 64 for thread=j). e-pass then x-pass (VGPR).
//   acc[b][hl] partials over 16 c's; reduce via shfl_xor(1,2); cndmask pick.
// P2: wave w: head n=w>>1, j-half jh=w&1; butterfly max/sum; unnormalized
//   probs transposed s_p[j][4]; 1/sum folded after P3.
// P3 (vectorized): lane=(g,cl): float4 rows, 4 rows/instr; acc[hl][u] over
//   c=cl*4+u; shfl-reduce over g (xor 16,32); lane<16 -> LDS atomicAdd.
// Epilogue: emb for our 128 dims -> out via global atomicAdd (out pre-zeroed).
// ---------------------------------------------------------------------------
__global__ __launch_bounds__(512, 4) void fused_kernel(
    const float* __restrict__ e, const float* __restrict__ x,
    const float* __restrict__ Wq, const float* __restrict__ Wk,
    const float* __restrict__ We, const float* __restrict__ Wv,
    const float* __restrict__ Wo, const float* __restrict__ bo,
    float* __restrict__ out) {
  const int t = threadIdx.x;
  const int i  = blockIdx.x & 511;  // query row
  const int hg = blockIdx.x >> 9;   // head-group: global heads hg*4..hg*4+3
  const int lane = t & 63, w = t >> 6;

  __shared__ float s_x[64];
  __shared__ __align__(16) float s_q[128];       // q, our 4 heads
  __shared__ __align__(16) float s_qce[256];     // e-coef [c][hl]
  __shared__ __align__(16) float s_qcx[256];     // x-coef [c][hl]
  __shared__ __align__(16) float s_p[4 * PSTR];  // logits -> probs[j][4] -> scratch
  __shared__ float s_red[8], s_red2[8], s_inv[4];
  __shared__ __align__(16) float s_ae[256];
  __shared__ __align__(16) float s_px[256];

  // ---- init + prologue
  if (t < 256) s_ae[t] = 0.f;
  else s_px[t - 256] = 0.f;
  if (t < 64) s_x[t] = x[i * 64 + t];
  __syncthreads();
  if (t < 128) {  // q for dims hg*128 .. hg*128+127
    const int d = hg * 128 + t;
    float a = 0;
#pragma unroll 8
    for (int c = 0; c < 64; ++c) a += s_x[c] * Wq[c * 256 + d];
    s_q[t] = a * SCALE;
  }
  __syncthreads();
  {  // coefs: c = t>>3, which = (t&7)>>2, hl = t&3
    const int c = t >> 3, hv = t & 7, which = hv >> 2, hl = hv & 3;
    const float* W = which ? Wk : We;
    const float4* wr = (const float4*)(W + c * 256 + (hg * 4 + hl) * 32);
    const float4* qr = (const float4*)(s_q + hl * 32);
    float s = 0;
#pragma unroll
    for (int u = 0; u < 8; ++u) {
      float4 wv = wr[u], qv = qr[u];
      s += qv.x * wv.x + qv.y * wv.y + qv.z * wv.z + qv.w * wv.w;
    }
    (which ? s_qcx : s_qce)[c * 4 + hl] = s;
  }
  __syncthreads();

  // ---- Phase 1: coalesced logits. lane=(jj,part); wave w rows [w*64,+64)
  {
    const int jj = lane >> 2, part = lane & 3;
    const float* eb = e + (size_t)(i * 512 + w * 64 + jj) * 64 + part * 4;
    const float* xb = x + (size_t)(w * 64 + jj) * 64 + part * 4;
    float acc[4][4];
#pragma unroll
    for (int b = 0; b < 4; ++b)
#pragma unroll
      for (int h = 0; h < 4; ++h) acc[b][h] = 0.f;
    // e-pass
#pragma unroll
    for (int seg = 0; seg < 4; ++seg) {
      const int c0 = seg * 16 + part * 4;
      float4 k0 = *(const float4*)(s_qce + (c0 + 0) * 4);
      float4 k1 = *(const float4*)(s_qce + (c0 + 1) * 4);
      float4 k2 = *(const float4*)(s_qce + (c0 + 2) * 4);
      float4 k3 = *(const float4*)(s_qce + (c0 + 3) * 4);
#pragma unroll
      for (int b = 0; b < 4; ++b) {
        float4 E = *(const float4*)(eb + b * 1024 + seg * 16);  // 16 rows x 1 line
        acc[b][0] += E.x * k0.x + E.y * k1.x + E.z * k2.x + E.w * k3.x;
        acc[b][1] += E.x * k0.y + E.y * k1.y + E.z * k2.y + E.w * k3.y;
        acc[b][2] += E.x * k0.z + E.y * k1.z + E.z * k2.z + E.w * k3.z;
        acc[b][3] += E.x * k0.w + E.y * k1.w + E.z * k2.w + E.w * k3.w;
      }
    }
    // x-pass
#pragma unroll
    for (int seg = 0; seg < 4; ++seg) {
      const int c0 = seg * 16 + part * 4;
      float4 k0 = *(const float4*)(s_qcx + (c0 + 0) * 4);
      float4 k1 = *(const float4*)(s_qcx + (c0 + 1) * 4);
      float4 k2 = *(const float4*)(s_qcx + (c0 + 2) * 4);
      float4 k3 = *(const float4*)(s_qcx + (c0 + 3) * 4);
#pragma unroll
      for (int b = 0; b < 4; ++b) {
        float4 X = *(const float4*)(xb + b * 1024 + seg * 16);
        acc[b][0] += X.x * k0.x + X.y * k1.x + X.z * k2.x + X.w * k3.x;
        acc[b][1] += X.x * k0.y + X.y * k1.y + X.z * k2.y + X.w * k3.y;
        acc[b][2] += X.x * k0.z + X.y * k1.z + X.z * k2.z + X.w * k3.z;
        acc[b][3] += X.x * k0.w + X.y * k1.w + X.z * k2.w + X.w * k3.w;
      }
    }
    // reduce over part (4-lane groups), writer lane part==hl
#pragma unroll
    for (int b = 0; b < 4; ++b) {
      float v0 = acc[b][0], v1 = acc[b][1], v2 = acc[b][2], v3 = acc[b][3];
      v0 += __shfl_xor(v0, 1, 64); v0 += __shfl_xor(v0, 2, 64);
      v1 += __shfl_xor(v1, 1, 64); v1 += __shfl_xor(v1, 2, 64);
      v2 += __shfl_xor(v2, 1, 64); v2 += __shfl_xor(v2, 2, 64);
      v3 += __shfl_xor(v3, 1, 64); v3 += __shfl_xor(v3, 2, 64);
      float v = (part == 0) ? v0 : (part == 1) ? v1 : (part == 2) ? v2 : v3;
      s_p[part * PSTR + (w * 64 + b * 16 + jj)] = v;
    }
  }
  __syncthreads();

  // ---- Phase 2: wave w: head n = w>>1, j-half jh = w&1 (256 j each)
  {
    const int n = w >> 1, jh = w & 1;
    const int jb = jh * 256 + lane;
    float lv[4];
    float m = -1e30f;
#pragma unroll
    for (int u = 0; u < 4; ++u) {
      lv[u] = s_p[n * PSTR + jb + u * 64];
      m = fmaxf(m, lv[u]);
    }
#pragma unroll
    for (int off = 32; off; off >>= 1) m = fmaxf(m, __shfl_xor(m, off, 64));
    if (lane == 0) s_red[w] = m;
    __syncthreads();  // all logit reads done; max partials visible
    const float M = fmaxf(s_red[n * 2], s_red[n * 2 + 1]);
    float sum = 0;
#pragma unroll
    for (int u = 0; u < 4; ++u) {
      lv[u] = __expf(lv[u] - M);
      sum += lv[u];
      s_p[(jb + u * 64) * 4 + n] = lv[u];  // unnormalized prob, transposed [j][4]
    }
#pragma unroll
    for (int off = 32; off; off >>= 1) sum += __shfl_xor(sum, off, 64);
    if (lane == 0) s_red2[w] = sum;
  }
  __syncthreads();
  if (t < 4) s_inv[t] = 1.0f / (s_red2[t * 2] + s_red2[t * 2 + 1]);
  // (s_inv consumed only after P3's closing barrier)

  // ---- Phase 3: vectorized. lane=(g=lane>>4, cl=lane&15); wave w rows [w*64,+64)
  {
    const int g = lane >> 4, cl = lane & 15;
    const float* ep = e + (size_t)i * 32768 + (size_t)(w * 64 + g) * 64 + cl * 4;
    const float* xp = x + (w * 64 + g) * 64 + cl * 4;
    float ae[4][4], px[4][4];
#pragma unroll
    for (int h = 0; h < 4; ++h)
#pragma unroll
      for (int u = 0; u < 4; ++u) { ae[h][u] = 0.f; px[h][u] = 0.f; }
#pragma unroll
    for (int it = 0; it < 16; ++it) {
      float4 E = *(const float4*)(ep + it * 256);  // 4 rows/instr, 16 lines, coalesced
      float4 X = *(const float4*)(xp + it * 256);
      float4 p = *(const float4*)(s_p + (w * 64 + it * 4 + g) * 4);
      ae[0][0] += p.x * E.x; ae[0][1] += p.x * E.y; ae[0][2] += p.x * E.z; ae[0][3] += p.x * E.w;
      ae[1][0] += p.y * E.x; ae[1][1] += p.y * E.y; ae[1][2] += p.y * E.z; ae[1][3] += p.y * E.w;
      ae[2][0] += p.z * E.x; ae[2][1] += p.z * E.y; ae[2][2] += p.z * E.z; ae[2][3] += p.z * E.w;
      ae[3][0] += p.w * E.x; ae[3][1] += p.w * E.y; ae[3][2] += p.w * E.z; ae[3][3] += p.w * E.w;
      px[0][0] += p.x * X.x; px[0][1] += p.x * X.y; px[0][2] += p.x * X.z; px[0][3] += p.x * X.w;
      px[1][0] += p.y * X.x; px[1][1] += p.y * X.y; px[1][2] += p.y * X.z; px[1][3] += p.y * X.w;
      px[2][0] += p.z * X.x; px[2][1] += p.z * X.y; px[2][2] += p.z * X.z; px[2][3] += p.z * X.w;
      px[3][0] += p.w * X.x; px[3][1] += p.w * X.y; px[3][2] += p.w * X.z; px[3][3] += p.w * X.w;
    }
    // reduce over g (xor 16, 32)
#pragma unroll
    for (int h = 0; h < 4; ++h)
#pragma unroll
      for (int u = 0; u < 4; ++u) {
        ae[h][u] += __shfl_xor(ae[h][u], 16, 64);
        ae[h][u] += __shfl_xor(ae[h][u], 32, 64);
        px[h][u] += __shfl_xor(px[h][u], 16, 64);
        px[h][u] += __shfl_xor(px[h][u], 32, 64);
      }
    if (lane < 16) {
#pragma unroll
      for (int h = 0; h < 4; ++h)
#pragma unroll
        for (int u = 0; u < 4; ++u) {
          atomicAdd(&s_ae[h * 64 + cl * 4 + u], ae[h][u]);
          atomicAdd(&s_px[h * 64 + cl * 4 + u], px[h][u]);
        }
    }
  }
  __syncthreads();

  // ---- fold softmax normalization
  if (t < 256) s_ae[t] *= s_inv[t >> 6];
  else s_px[t - 256] *= s_inv[(t - 256) >> 6];
  __syncthreads();

  // ---- Epilogue (scratch aliases the now-dead s_p)
  float* s_eb  = s_p;        // 512 floats
  float* s_emb = s_p + 512;  // 128 floats
  float* s_op  = s_p + 768;  // 512 floats
  {
    const int nd = t & 127, ch = t >> 7, hl = nd >> 5;
    const int gnd = hg * 128 + nd;
    float emb = 0;
    const int cb = ch * 16;
#pragma unroll
    for (int c = cb; c < cb + 16; ++c)
      emb += s_ae[hl * 64 + c] * We[c * 256 + gnd] + s_px[hl * 64 + c] * Wv[c * 256 + gnd];
    s_eb[ch * 128 + nd] = emb;
  }
  __syncthreads();
  if (t < 128) s_emb[t] = s_eb[t] + s_eb[128 + t] + s_eb[256 + t] + s_eb[384 + t];
  __syncthreads();
  {
    const int o = t & 63, mc = t >> 6;
    float oo = 0;
#pragma unroll
    for (int m2 = mc * 16; m2 < mc * 16 + 16; ++m2)
      oo += s_emb[m2] * Wo[(hg * 128 + m2) * 64 + o];
    s_op[mc * 64 + o] = oo;
  }
  __syncthreads();
  if (t < 64) {
    float r = 0;
#pragma unroll
    for (int w2 = 0; w2 < 8; ++w2) r += s_op[w2 * 64 + t];
    if (hg == 0) r += bo[t];
    atomicAdd(&out[i * 64 + t], r);  // out pre-zeroed by memset
  }
}

extern "C" void kernel_launch(void* const* d_in, const int* in_sizes, int n_in,
                              void* d_out, int out_size, void* d_ws, size_t ws_size,
                              hipStream_t stream) {
  const float* x  = (const float*)d_in[0];
  const float* e  = (const float*)d_in[1];
  const float* Wq = (const float*)d_in[2];
  const float* Wk = (const float*)d_in[3];
  const float* Wv = (const float*)d_in[4];
  const float* We = (const float*)d_in[5];
  const float* Wo = (const float*)d_in[6];
  const float* bo = (const float*)d_in[7];
  float* out = (float*)d_out;

  hipMemsetAsync(d_out, 0, out_size, stream);
  hipLaunchKernelGGL(fused_kernel, dim3(1024), dim3(512), 0, stream,
                     e, x, Wq, Wk, We, Wv, Wo, bo, out);
}

// Round 12
// 173.982 us; speedup vs baseline: 1.7793x; 1.7793x over previous
//
#include <hip/hip_runtime.h>

#define SCALE 0.17677669529663687f  // 1/sqrt(32)
#define PSTR 513                    // padded s_p row stride (bank spread)

// ---------------------------------------------------------------------------
// One block per query row i. 512 blocks x 512 thr (8 waves). Round-0 skeleton
// (proven 139.5 us) with P1 restructured to eliminate the LDS-pipe bottleneck:
// r0's P1 issued ~1024 uniform ds_read_b32 of the coef table per thread
// (~5.9Kcy/wave; x16 waves sharing the CU LDS pipe ~= 40us serialized).
//
// P1 (new): lane=c. Each lane holds its 16 coefs in VGPRs (loaded once).
//   Wave w owns j in [w*64,+64). Per j: coalesced e/x scalar loads (256B/wave,
//   also fixes r0's 64-line/instr amplification), 16 FMA, then 8-value
//   reduce-scatter over lanes (7 shfl, DPP) + butterfly xor8/16/32; lane h<8
//   writes logit[h][j]. Zero LDS reads in the inner loop.
// P2/P3/epilogue: round-0 verbatim.
// ---------------------------------------------------------------------------
__global__ __launch_bounds__(512, 4) void fused_kernel(
    const float* __restrict__ e, const float* __restrict__ x,
    const float* __restrict__ Wq, const float* __restrict__ Wk,
    const float* __restrict__ We, const float* __restrict__ Wv,
    const float* __restrict__ Wo, const float* __restrict__ bo,
    float* __restrict__ out) {
  const int t = threadIdx.x, i = blockIdx.x;
  const int lane = t & 63, w = t >> 6;
  __shared__ float s_x[64];
  __shared__ __align__(16) float s_q[256];
  __shared__ __align__(16) float s_qc[1024];       //  4 KB coefs [c][{e:8,x:8}]
  __shared__ __align__(16) float s_p[8 * PSTR];    // ~16 KB logits
  __shared__ __align__(16) float s_pt[512 * 8];    // 16 KB probs transposed [j][h]
  __shared__ __align__(16) float s_part[8 * 1024]; // 32 KB wave partials (ae|px)
  __shared__ float s_ae[512], s_px[512];
  __shared__ float s_emb[256];
  __shared__ float s_op[8 * 64];

  // ---- Prologue: coefficients
  if (t < 64) s_x[t] = x[i * 64 + t];
  __syncthreads();
  if (t < 256) {
    float a = 0;
#pragma unroll 8
    for (int c = 0; c < 64; ++c) a += s_x[c] * Wq[c * 256 + t];
    s_q[t] = a * SCALE;
  }
  __syncthreads();
  {
    const int c = t >> 3, h = t & 7;
    const float4* wer = (const float4*)(We + c * 256 + h * 32);
    const float4* wkr = (const float4*)(Wk + c * 256 + h * 32);
    const float4* qr = (const float4*)(s_q + h * 32);
    float se = 0, sk = 0;
#pragma unroll
    for (int u = 0; u < 8; ++u) {
      float4 w1 = wer[u], w2 = wkr[u], qv = qr[u];
      se += qv.x * w1.x + qv.y * w1.y + qv.z * w1.z + qv.w * w1.w;
      sk += qv.x * w2.x + qv.y * w2.y + qv.z * w2.z + qv.w * w2.w;
    }
    s_qc[c * 16 + h] = se;
    s_qc[c * 16 + 8 + h] = sk;
  }
  __syncthreads();

  // ---- Phase 1: lane=c; coefs in registers; wave w owns j in [w*64,+64)
  {
    float4 ce0 = *(const float4*)(s_qc + lane * 16);      // e-coefs h0..3
    float4 ce1 = *(const float4*)(s_qc + lane * 16 + 4);  // e-coefs h4..7
    float4 cx0 = *(const float4*)(s_qc + lane * 16 + 8);  // x-coefs h0..3
    float4 cx1 = *(const float4*)(s_qc + lane * 16 + 12); // x-coefs h4..7
    const float* ep = e + (size_t)i * 32768 + (size_t)w * 4096 + lane;
    const float* xp = x + w * 4096 + lane;
    const int b0 = lane & 1, b1 = lane & 2, b2 = lane & 4;
#pragma unroll 4
    for (int jj = 0; jj < 64; ++jj) {
      float ev = ep[jj * 64];          // coalesced 256B/wave
      float xv = xp[jj * 64];
      float v0 = ev * ce0.x + xv * cx0.x;
      float v1 = ev * ce0.y + xv * cx0.y;
      float v2 = ev * ce0.z + xv * cx0.z;
      float v3 = ev * ce0.w + xv * cx0.w;
      float v4 = ev * ce1.x + xv * cx1.x;
      float v5 = ev * ce1.y + xv * cx1.y;
      float v6 = ev * ce1.z + xv * cx1.z;
      float v7 = ev * ce1.w + xv * cx1.w;
      // reduce-scatter over lane bits 0-2: lane ends with h = lane&7 partial
      float r0 = (b0 ? v1 : v0) + __shfl_xor(b0 ? v0 : v1, 1, 64);
      float r1 = (b0 ? v3 : v2) + __shfl_xor(b0 ? v2 : v3, 1, 64);
      float r2 = (b0 ? v5 : v4) + __shfl_xor(b0 ? v4 : v5, 1, 64);
      float r3 = (b0 ? v7 : v6) + __shfl_xor(b0 ? v6 : v7, 1, 64);
      float q0 = (b1 ? r1 : r0) + __shfl_xor(b1 ? r0 : r1, 2, 64);
      float q1 = (b1 ? r3 : r2) + __shfl_xor(b1 ? r2 : r3, 2, 64);
      float f  = (b2 ? q1 : q0) + __shfl_xor(b2 ? q0 : q1, 4, 64);
      // combine the 8 lane-groups
      f += __shfl_xor(f, 8, 64);
      f += __shfl_xor(f, 16, 64);
      f += __shfl_xor(f, 32, 64);
      if (lane < 8) s_p[lane * PSTR + w * 64 + jj] = f;
    }
  }
  __syncthreads();

  // ---- Phase 2: softmax per head (64 lanes/head); write transposed probs
  {
    const int n = t >> 6, l64 = t & 63;
    float m = -1e30f;
#pragma unroll
    for (int u = 0; u < 8; ++u) m = fmaxf(m, s_p[n * PSTR + l64 + u * 64]);
#pragma unroll
    for (int off = 32; off; off >>= 1) m = fmaxf(m, __shfl_xor(m, off, 64));
    float pv[8];
    float sum = 0;
#pragma unroll
    for (int u = 0; u < 8; ++u) {
      pv[u] = __expf(s_p[n * PSTR + l64 + u * 64] - m);
      sum += pv[u];
    }
#pragma unroll
    for (int off = 32; off; off >>= 1) sum += __shfl_xor(sum, off, 64);
    const float inv = 1.0f / sum;
#pragma unroll
    for (int u = 0; u < 8; ++u) s_pt[(l64 + u * 64) * 8 + n] = pv[u] * inv;
  }
  __syncthreads();

  // ---- Phase 3: lane=c, wave w owns j in [w*64, w*64+64)
  {
    float ae[8], px[8];
#pragma unroll
    for (int h = 0; h < 8; ++h) { ae[h] = 0.f; px[h] = 0.f; }
    const float* ep = e + (size_t)i * 32768 + (size_t)w * 4096 + lane;
    const float* xp = x + w * 4096 + lane;
#pragma unroll 4
    for (int jj = 0; jj < 64; ++jj) {
      const int j = w * 64 + jj;
      float ev = ep[jj * 64];          // coalesced 256B/wave
      float xv = xp[jj * 64];
      const float4* pt = (const float4*)(s_pt + j * 8);  // uniform -> broadcast
      float4 p0 = pt[0], p1 = pt[1];
      ae[0] += p0.x * ev; ae[1] += p0.y * ev; ae[2] += p0.z * ev; ae[3] += p0.w * ev;
      ae[4] += p1.x * ev; ae[5] += p1.y * ev; ae[6] += p1.z * ev; ae[7] += p1.w * ev;
      px[0] += p0.x * xv; px[1] += p0.y * xv; px[2] += p0.z * xv; px[3] += p0.w * xv;
      px[4] += p1.x * xv; px[5] += p1.y * xv; px[6] += p1.z * xv; px[7] += p1.w * xv;
    }
#pragma unroll
    for (int h = 0; h < 8; ++h) {
      s_part[w * 1024 + h * 64 + lane] = ae[h];
      s_part[w * 1024 + 512 + h * 64 + lane] = px[h];
    }
  }
  __syncthreads();

  // reduce the 8 wave partials
  {
    float va = 0, vp = 0;
#pragma unroll
    for (int w2 = 0; w2 < 8; ++w2) {
      va += s_part[w2 * 1024 + t];
      vp += s_part[w2 * 1024 + 512 + t];
    }
    s_ae[t] = va; s_px[t] = vp;
  }
  __syncthreads();

  // ---- Epilogue: emb[nd] = sum_c ae[n,c]We[c,nd] + px[n,c]Wv[c,nd]
  {
    const int nd = t & 255, ch = t >> 8, hn = nd >> 5;
    float emb = 0;
    const int cb = ch * 32;
#pragma unroll 8
    for (int c = cb; c < cb + 32; ++c)
      emb += s_ae[hn * 64 + c] * We[c * 256 + nd] + s_px[hn * 64 + c] * Wv[c * 256 + nd];
    s_part[ch * 256 + nd] = emb;
  }
  __syncthreads();
  if (t < 256) s_emb[t] = s_part[t] + s_part[256 + t];
  __syncthreads();
  // out[o] = sum_m emb[m]*Wo[m,o] + bo[o]
  {
    const int o = t & 63, mc = t >> 6;
    float oo = 0;
#pragma unroll 8
    for (int m2 = mc * 32; m2 < mc * 32 + 32; ++m2) oo += s_emb[m2] * Wo[m2 * 64 + o];
    s_op[mc * 64 + o] = oo;
  }
  __syncthreads();
  if (t < 64) {
    float r = bo[t];
#pragma unroll
    for (int w2 = 0; w2 < 8; ++w2) r += s_op[w2 * 64 + t];
    out[i * 64 + t] = r;
  }
}

extern "C" void kernel_launch(void* const* d_in, const int* in_sizes, int n_in,
                              void* d_out, int out_size, void* d_ws, size_t ws_size,
                              hipStream_t stream) {
  const float* x  = (const float*)d_in[0];
  const float* e  = (const float*)d_in[1];
  const float* Wq = (const float*)d_in[2];
  const float* Wk = (const float*)d_in[3];
  const float* Wv = (const float*)d_in[4];
  const float* We = (const float*)d_in[5];
  const float* Wo = (const float*)d_in[6];
  const float* bo = (const float*)d_in[7];
  float* out = (float*)d_out;

  hipLaunchKernelGGL(fused_kernel, dim3(512), dim3(512), 0, stream,
                     e, x, Wq, Wk, We, Wv, Wo, bo, out);
}

// Round 13
// 163.846 us; speedup vs baseline: 1.8894x; 1.0619x over previous
//
#include <hip/hip_runtime.h>

#define SCALE 0.17677669529663687f  // 1/sqrt(32)
#define PSTR 513                    // padded s_p row stride (bank spread)

// ---------------------------------------------------------------------------
// Round-0 skeleton (proven best: 55us dispatch). One block per query row i,
// 512 blocks x 512 thr. Single change vs r0: P1 coef reads are b128 uniform
// broadcasts (256/wave) instead of scalar b32 (1024/wave), with head-halved
// processing to keep <=64 VGPR (r5's 16-float-live variant spilled 29MB).
//
// s_qc layout per channel c (16 floats): [e-coef h0..7 | x-coef h0..7]
//   -> as float4: qcv[4k]=e h0-3, [4k+1]=e h4-7, [4k+2]=x h0-3, [4k+3]=x h4-7
// ---------------------------------------------------------------------------
__global__ __launch_bounds__(512, 4) void fused_kernel(
    const float* __restrict__ e, const float* __restrict__ x,
    const float* __restrict__ Wq, const float* __restrict__ Wk,
    const float* __restrict__ We, const float* __restrict__ Wv,
    const float* __restrict__ Wo, const float* __restrict__ bo,
    float* __restrict__ out) {
  const int t = threadIdx.x, i = blockIdx.x;
  __shared__ float s_x[64];
  __shared__ __align__(16) float s_q[256];
  __shared__ __align__(16) float s_qc[1024];       //  4 KB coefs
  __shared__ __align__(16) float s_p[8 * PSTR];    // ~16 KB logits
  __shared__ __align__(16) float s_pt[512 * 8];    // 16 KB probs transposed [j][h]
  __shared__ __align__(16) float s_part[8 * 1024]; // 32 KB wave partials (ae|px)
  __shared__ float s_ae[512], s_px[512];
  __shared__ float s_emb[256];
  __shared__ float s_op[8 * 64];

  // ---- Prologue: coefficients
  if (t < 64) s_x[t] = x[i * 64 + t];
  __syncthreads();
  if (t < 256) {
    float a = 0;
#pragma unroll 8
    for (int c = 0; c < 64; ++c) a += s_x[c] * Wq[c * 256 + t];
    s_q[t] = a * SCALE;
  }
  __syncthreads();
  {
    const int c = t >> 3, h = t & 7;
    const float4* wer = (const float4*)(We + c * 256 + h * 32);
    const float4* wkr = (const float4*)(Wk + c * 256 + h * 32);
    const float4* qr = (const float4*)(s_q + h * 32);
    float se = 0, sk = 0;
#pragma unroll
    for (int u = 0; u < 8; ++u) {
      float4 w1 = wer[u], w2 = wkr[u], qv = qr[u];
      se += qv.x * w1.x + qv.y * w1.y + qv.z * w1.z + qv.w * w1.w;
      sk += qv.x * w2.x + qv.y * w2.y + qv.z * w2.z + qv.w * w2.w;
    }
    s_qc[c * 16 + h] = se;
    s_qc[c * 16 + 8 + h] = sk;
  }
  __syncthreads();

  // ---- Phase 1: one j per thread; coefs via b128 uniform broadcast
  {
    const int j = t;
    const float4* erow = (const float4*)(e + (size_t)(i * 512 + j) * 64);
    const float4* xrow = (const float4*)(x + j * 64);
    float acc[8];
#pragma unroll
    for (int h = 0; h < 8; ++h) acc[h] = 0.f;
#pragma unroll 2
    for (int c4 = 0; c4 < 16; ++c4) {
      float4 E = erow[c4];
      float4 X = xrow[c4];
      const float4* qcv = (const float4*)(s_qc + c4 * 64);  // 4 channels x 4 f4
#define CH4(Ec, Xc, IA, IB, O)                                   \
  { float4 A_ = qcv[IA], B_ = qcv[IB];                           \
    acc[(O) + 0] += Ec * A_.x + Xc * B_.x;                       \
    acc[(O) + 1] += Ec * A_.y + Xc * B_.y;                       \
    acc[(O) + 2] += Ec * A_.z + Xc * B_.z;                       \
    acc[(O) + 3] += Ec * A_.w + Xc * B_.w; }
      // heads 0-3 (8 coef floats live at a time)
      CH4(E.x, X.x, 0, 2, 0)  CH4(E.y, X.y, 4, 6, 0)
      CH4(E.z, X.z, 8, 10, 0) CH4(E.w, X.w, 12, 14, 0)
      // heads 4-7
      CH4(E.x, X.x, 1, 3, 4)  CH4(E.y, X.y, 5, 7, 4)
      CH4(E.z, X.z, 9, 11, 4) CH4(E.w, X.w, 13, 15, 4)
#undef CH4
    }
#pragma unroll
    for (int h = 0; h < 8; ++h) s_p[h * PSTR + j] = acc[h];
  }
  __syncthreads();

  // ---- Phase 2: softmax per head (64 lanes/head); write transposed probs
  {
    const int n = t >> 6, l64 = t & 63;
    float m = -1e30f;
#pragma unroll
    for (int u = 0; u < 8; ++u) m = fmaxf(m, s_p[n * PSTR + l64 + u * 64]);
#pragma unroll
    for (int off = 32; off; off >>= 1) m = fmaxf(m, __shfl_xor(m, off, 64));
    float pv[8];
    float sum = 0;
#pragma unroll
    for (int u = 0; u < 8; ++u) {
      pv[u] = __expf(s_p[n * PSTR + l64 + u * 64] - m);
      sum += pv[u];
    }
#pragma unroll
    for (int off = 32; off; off >>= 1) sum += __shfl_xor(sum, off, 64);
    const float inv = 1.0f / sum;
#pragma unroll
    for (int u = 0; u < 8; ++u) s_pt[(l64 + u * 64) * 8 + n] = pv[u] * inv;
  }
  __syncthreads();

  // ---- Phase 3: lane=c, wave w owns j in [w*64, w*64+64)
  {
    const int lane = t & 63, w = t >> 6;
    float ae[8], px[8];
#pragma unroll
    for (int h = 0; h < 8; ++h) { ae[h] = 0.f; px[h] = 0.f; }
    const float* ep = e + (size_t)i * 32768 + (size_t)w * 4096 + lane;
    const float* xp = x + w * 4096 + lane;
#pragma unroll 4
    for (int jj = 0; jj < 64; ++jj) {
      const int j = w * 64 + jj;
      float ev = ep[jj * 64];          // coalesced 256B/wave
      float xv = xp[jj * 64];
      const float4* pt = (const float4*)(s_pt + j * 8);  // uniform -> broadcast
      float4 p0 = pt[0], p1 = pt[1];
      ae[0] += p0.x * ev; ae[1] += p0.y * ev; ae[2] += p0.z * ev; ae[3] += p0.w * ev;
      ae[4] += p1.x * ev; ae[5] += p1.y * ev; ae[6] += p1.z * ev; ae[7] += p1.w * ev;
      px[0] += p0.x * xv; px[1] += p0.y * xv; px[2] += p0.z * xv; px[3] += p0.w * xv;
      px[4] += p1.x * xv; px[5] += p1.y * xv; px[6] += p1.z * xv; px[7] += p1.w * xv;
    }
#pragma unroll
    for (int h = 0; h < 8; ++h) {
      s_part[w * 1024 + h * 64 + lane] = ae[h];
      s_part[w * 1024 + 512 + h * 64 + lane] = px[h];
    }
  }
  __syncthreads();

  // reduce the 8 wave partials
  {
    float va = 0, vp = 0;
#pragma unroll
    for (int w = 0; w < 8; ++w) {
      va += s_part[w * 1024 + t];
      vp += s_part[w * 1024 + 512 + t];
    }
    s_ae[t] = va; s_px[t] = vp;
  }
  __syncthreads();

  // ---- Epilogue: emb[nd] = sum_c ae[n,c]We[c,nd] + px[n,c]Wv[c,nd]
  {
    const int nd = t & 255, ch = t >> 8, hn = nd >> 5;
    float emb = 0;
    const int cb = ch * 32;
#pragma unroll 8
    for (int c = cb; c < cb + 32; ++c)
      emb += s_ae[hn * 64 + c] * We[c * 256 + nd] + s_px[hn * 64 + c] * Wv[c * 256 + nd];
    s_part[ch * 256 + nd] = emb;
  }
  __syncthreads();
  if (t < 256) s_emb[t] = s_part[t] + s_part[256 + t];
  __syncthreads();
  // out[o] = sum_m emb[m]*Wo[m,o] + bo[o]
  {
    const int o = t & 63, mc = t >> 6;
    float oo = 0;
#pragma unroll 8
    for (int m2 = mc * 32; m2 < mc * 32 + 32; ++m2) oo += s_emb[m2] * Wo[m2 * 64 + o];
    s_op[mc * 64 + o] = oo;
  }
  __syncthreads();
  if (t < 64) {
    float r = bo[t];
#pragma unroll
    for (int w = 0; w < 8; ++w) r += s_op[w * 64 + t];
    out[i * 64 + t] = r;
  }
}

extern "C" void kernel_launch(void* const* d_in, const int* in_sizes, int n_in,
                              void* d_out, int out_size, void* d_ws, size_t ws_size,
                              hipStream_t stream) {
  const float* x  = (const float*)d_in[0];
  const float* e  = (const float*)d_in[1];
  const float* Wq = (const float*)d_in[2];
  const float* Wk = (const float*)d_in[3];
  const float* Wv = (const float*)d_in[4];
  const float* We = (const float*)d_in[5];
  const float* Wo = (const float*)d_in[6];
  const float* bo = (const float*)d_in[7];
  float* out = (float*)d_out;

  hipLaunchKernelGGL(fused_kernel, dim3(512), dim3(512), 0, stream,
                     e, x, Wq, Wk, We, Wv, Wo, bo, out);
}